// Round 9
// baseline (161.585 us; speedup 1.0000x reference)
//
#include <hip/hip_runtime.h>
#include <cstdint>
#include <cstddef>

#define HID 1024
#define NH 16
#define HD 64
#define BB 2
#define LL 2048
#define MM (BB*LL)       // 4096 rows
#define CHUNK 64
#define NSEG 16          // segments per (b,h): 128 rows each (2 chunks)
#define BHn (BB*NH)      // 32 (b,h) chains
#define SP 72            // LDS pad stride (multiple of 8 for b128 reads)

typedef __bf16 bf16;
typedef __attribute__((ext_vector_type(8))) __bf16 bf16x8;
typedef __attribute__((ext_vector_type(4))) float f32x4;

__device__ __forceinline__ f32x4 mfma16(bf16x8 a, bf16x8 b, f32x4 c){
  return __builtin_amdgcn_mfma_f32_16x16x32_bf16(a, b, c, 0, 0, 0);
}

__device__ __forceinline__ void gload16(const void* g, void* l){
  __builtin_amdgcn_global_load_lds(
      (const __attribute__((address_space(1))) unsigned int*)g,
      (__attribute__((address_space(3))) unsigned int*)l, 16, 0, 0);
}

__device__ __forceinline__ void barx(){
  asm volatile("" ::: "memory");
  __builtin_amdgcn_s_barrier();
  asm volatile("" ::: "memory");
}

#define WAITVM(N) asm volatile("s_waitcnt vmcnt(" #N ")" ::: "memory")

// ---------------- fused cast fp32 -> bf16, 8 elems/thread ----------------
__global__ __launch_bounds__(256) void cast_all_k(
    const float* __restrict__ x,  const float* __restrict__ w0,
    const float* __restrict__ w1, const float* __restrict__ w2, const float* __restrict__ w3,
    bf16* __restrict__ xb, bf16* __restrict__ d0, bf16* __restrict__ d1,
    bf16* __restrict__ d2, bf16* __restrict__ d3)
{
  int bid = blockIdx.x;                   // 0..4095
  const float* s; bf16* d; int base;
  if (bid < 2048){ s = x; d = xb; base = bid; }           // 4M elems
  else {
    int w = (bid - 2048) >> 9, r = (bid - 2048) & 511;    // 1M elems each
    s = (w==0)?w0:(w==1)?w1:(w==2)?w2:w3;
    d = (w==0)?d0:(w==1)?d1:(w==2)?d2:d3;
    base = r;
  }
  size_t i = (size_t)(base*256 + threadIdx.x) * 8;
  float4 v0 = *(const float4*)(s + i);
  float4 v1 = *(const float4*)(s + i + 4);
  union { bf16 h[8]; uint4 u; } pk;
  pk.h[0]=(bf16)v0.x; pk.h[1]=(bf16)v0.y; pk.h[2]=(bf16)v0.z; pk.h[3]=(bf16)v0.w;
  pk.h[4]=(bf16)v1.x; pk.h[5]=(bf16)v1.y; pk.h[6]=(bf16)v1.z; pk.h[7]=(bf16)v1.w;
  *(uint4*)(d + i) = pk.u;
}

// ---------------- software-pipelined 8-wave 128x128 GEMM ----------------
// MODE 0: QKV fused, grid (24,32): wsel=bn>>3 picks Wq/Wk/Wv, bn&=7; elu+1 on Q,K.
//   Q -> row-major (M,HID). K -> row-major (M,HID) AND transposed Kt (BH,D,L).
//   V -> transposed Vt (BH,D,L) only. Transposes go through an in-LDS 128x128
//   tile (reuses the staging LDS after the K-loop; coalesced 16B stores out).
// MODE 1: out-proj, grid (8,32), fp32 store.
template<int MODE>
__global__ __launch_bounds__(512, 2) void gemm8_k(
    const bf16* __restrict__ A,
    const bf16* __restrict__ W0, const bf16* __restrict__ W1, const bf16* __restrict__ W2,
    bf16* __restrict__ Qo, bf16* __restrict__ Kn, bf16* __restrict__ Kt,
    bf16* __restrict__ Vt, float* __restrict__ Outf)
{
  constexpr int NKT = HID/32;
  __shared__ bf16 lds[4][2][128*32];               // 64 KiB

  const int tid = threadIdx.x;
  const int wv = tid >> 6, lane = tid & 63;
  const int lrow = lane & 15, g4 = lane >> 4;
  const int wr = wv >> 2, wc = wv & 3;
  int bn = blockIdx.x, wsel = 0;
  const bf16* W = W0;
  if (MODE==0){ wsel = bn >> 3; bn &= 7; W = (wsel==0)?W0:((wsel==1)?W1:W2); }
  const int row0 = blockIdx.y*128, col0 = bn*128;

  const int sr = tid >> 2, sc = tid & 3;
  const int scs = sc ^ ((sr>>1)&3);              // pre-swizzled source chunk
  const bf16* gA = A + (size_t)(row0 + sr)*HID + scs*8;
  const bf16* gB = W + (size_t)(col0 + sr)*HID + scs*8;
  const int ldst = tid*8;

  auto stage_tile = [&](int u){
    const int buf = u & 3;
    gload16(gA + u*32, (void*)&lds[buf][0][ldst]);
    gload16(gB + u*32, (void*)&lds[buf][1][ldst]);
  };

  const int koff = (g4 ^ ((lrow>>1)&3)) << 3;    // swizzled chunk on read

  auto read_frags = [&](int u, bf16x8 (&fa)[4], bf16x8 (&fb)[2]){
    const int buf = u & 3;
    #pragma unroll
    for (int i=0;i<4;i++)
      fa[i] = *(const bf16x8*)&lds[buf][0][((wr*64 + i*16+lrow)<<5) + koff];
    #pragma unroll
    for (int j=0;j<2;j++)
      fb[j] = *(const bf16x8*)&lds[buf][1][((wc*32 + j*16+lrow)<<5) + koff];
  };

  f32x4 acc[4][2] = {};
  auto do_mfma = [&](bf16x8 (&fa)[4], bf16x8 (&fb)[2]){
    __builtin_amdgcn_s_setprio(1);
    #pragma unroll
    for (int i=0;i<4;i++)
      #pragma unroll
      for (int j=0;j<2;j++)
        acc[i][j] = mfma16(fa[i], fb[j], acc[i][j]);
    __builtin_amdgcn_s_setprio(0);
  };

  stage_tile(0); stage_tile(1); stage_tile(2);
  WAITVM(4);
  barx();
  bf16x8 fEa[4], fEb[2], fOa[4], fOb[2];
  read_frags(0, fEa, fEb);

  for (int t=0; t<NKT; t+=2){
    if (t+3 < NKT)      { stage_tile(t+3); WAITVM(4); }
    else if (t+3 == NKT){ WAITVM(2); }
    else                { WAITVM(0); }
    barx();
    read_frags(t+1, fOa, fOb);
    do_mfma(fEa, fEb);
    const int t2 = t+1;
    if (t2 < NKT-1){
      if (t2+3 < NKT)      { stage_tile(t2+3); WAITVM(4); }
      else if (t2+3 == NKT){ WAITVM(2); }
      else                 { WAITVM(0); }
      barx();
      read_frags(t2+1, fEa, fEb);
    }
    do_mfma(fOa, fOb);
  }

  if (MODE==1){
    #pragma unroll
    for (int i=0;i<4;i++){
      const int m0 = row0 + wr*64 + i*16 + g4*4;
      #pragma unroll
      for (int j=0;j<2;j++){
        const int c = col0 + wc*32 + j*16 + lrow;
        #pragma unroll
        for (int r=0;r<4;r++)
          Outf[(size_t)(m0+r)*HID + c] = acc[i][j][r];
      }
    }
  } else if (wsel==0){
    // Q: elu+1, row-major store
    #pragma unroll
    for (int i=0;i<4;i++){
      const int m0 = row0 + wr*64 + i*16 + g4*4;
      #pragma unroll
      for (int j=0;j<2;j++){
        const int c = col0 + wc*32 + j*16 + lrow;
        #pragma unroll
        for (int r=0;r<4;r++){
          float v = acc[i][j][r];
          v = v>0.f ? v+1.f : __expf(v);
          Qo[(size_t)(m0+r)*HID + c] = (bf16)v;
        }
      }
    }
  } else {
    // K (elu+1) or V: transpose via LDS tile T[128 cols][136 pad] -> Kt/Vt (BH,D,L)
    bf16* T = &lds[0][0][0];                       // 128*136*2B = 34.8 KiB, fits
    barx();                                        // all K-loop LDS reads done
    #pragma unroll
    for (int i=0;i<4;i++){
      const int ml0 = wr*64 + i*16 + g4*4;
      const int m0  = row0 + ml0;
      #pragma unroll
      for (int j=0;j<2;j++){
        const int cc = wc*32 + j*16 + lrow;
        #pragma unroll
        for (int r=0;r<4;r++){
          float v = acc[i][j][r];
          if (wsel==1) v = v>0.f ? v+1.f : __expf(v);
          bf16 bv = (bf16)v;
          if (wsel==1) Kn[(size_t)(m0+r)*HID + (col0+cc)] = bv;
          T[cc*136 + ml0 + r] = bv;
        }
      }
    }
    barx();
    // coalesced store: thread tid -> column cc=tid>>2, l-range (tid&3)*32..+32
    bf16* dst = (wsel==1) ? Kt : Vt;
    const int cc = tid >> 2, mlb = (tid & 3) * 32;
    const int cgl = col0 + cc;
    const int hh = cgl >> 6, dd = cgl & 63;
    const int bseq = row0 >> 11, lbase = (row0 & (LL-1)) + mlb;
    size_t base = ((size_t)((bseq*NH + hh)*HD + dd))*LL + lbase;
    #pragma unroll
    for (int u=0;u<4;u++)
      *(bf16x8*)&dst[base + u*8] = *(const bf16x8*)&T[cc*136 + mlb + u*8];
  }
}

// ---------------- segsum: per-(b,h,seg) S^T[e][d] over 128 rows + ksum ----------------
// grid = BHn*NSEG = 512 blocks x 256 thr. No LDS, no syncs: frags straight from
// Kt/Vt (BH,D,L). Wave we owns e-strip [we*16,we*16+16).
__global__ __launch_bounds__(256) void segsum_k(const bf16* __restrict__ Kt, const bf16* __restrict__ Vt,
                                                float* __restrict__ Sseg, float* __restrict__ kseg)
{
  const int bx = blockIdx.x;
  const int bh = bx >> 4, seg = bx & (NSEG-1);
  const int tid = threadIdx.x;
  const int we = tid >> 6, lane = tid & 63;
  const int lrow = lane&15, g4 = lane>>4, lk8 = g4*8;
  const bf16* ktb = Kt + (size_t)bh*HD*LL + seg*128;
  const bf16* vtb = Vt + (size_t)bh*HD*LL + seg*128;

  f32x4 acc[4] = {};
  #pragma unroll
  for (int kk=0;kk<4;kk++){
    bf16x8 fa = *(const bf16x8*)&vtb[(size_t)(we*16+lrow)*LL + kk*32 + lk8];
    #pragma unroll
    for (int j=0;j<4;j++){
      bf16x8 fb = *(const bf16x8*)&ktb[(size_t)(j*16+lrow)*LL + kk*32 + lk8];
      acc[j] = mfma16(fa, fb, acc[j]);
    }
  }
  float* so = Sseg + (size_t)bx*4096;
  #pragma unroll
  for (int j=0;j<4;j++)
    #pragma unroll
    for (int r=0;r<4;r++)
      so[(we*16 + g4*4 + r)*64 + j*16 + lrow] = acc[j][r];

  // ksum rows d = we*16+lrow, l split by g4 (32 each)
  {
    float s = 0.f;
    const bf16* kr = ktb + (size_t)(we*16+lrow)*LL + g4*32;
    #pragma unroll
    for (int u=0;u<4;u++){
      bf16x8 k8 = *(const bf16x8*)&kr[u*8];
      #pragma unroll
      for (int e=0;e<8;e++) s += (float)k8[e];
    }
    s += __shfl_xor(s,16); s += __shfl_xor(s,32);
    if (g4==0) kseg[(size_t)bx*64 + we*16 + lrow] = s;
  }
}

// ---------------- segscan: exclusive prefix over NSEG segments ----------------
__global__ __launch_bounds__(256) void segscan_k(const float* __restrict__ Sseg, const float* __restrict__ kseg,
                                                 bf16* __restrict__ Sexb, float* __restrict__ ksxb)
{
  int gid = blockIdx.x*256 + threadIdx.x;
  if (gid < BHn*4096){
    int bh = gid >> 12, e = gid & 4095;
    float run = 0.f;
    size_t base = (size_t)bh*NSEG*4096 + e;
    #pragma unroll 4
    for (int s=0;s<NSEG;s++){
      Sexb[base + (size_t)s*4096] = (bf16)run;
      run += Sseg[base + (size_t)s*4096];
    }
  } else if (gid < BHn*4096 + BHn*64){
    int g2 = gid - BHn*4096;
    int bh = g2 >> 6, d = g2 & 63;
    float run = 0.f;
    size_t base = (size_t)bh*NSEG*64 + d;
    #pragma unroll 4
    for (int s=0;s<NSEG;s++){
      ksxb[base + (size_t)s*64] = run;
      run += kseg[base + (size_t)s*64];
    }
  }
}

// ---------------- attn: per-(b,h,seg) output for 2 chunks, state on-chip ----------
// LDS = P + Sm + ksum only (18.7 KB). K^T/V^T frags direct from Kt/Vt (global).
// 2 syncthreads per chunk.
__global__ __launch_bounds__(256, 2) void attn_k(const bf16* __restrict__ Q, const bf16* __restrict__ Kn,
                                                 const bf16* __restrict__ Kt, const bf16* __restrict__ Vt,
                                                 const bf16* __restrict__ Sexb, const float* __restrict__ ksxb,
                                                 bf16* __restrict__ Obuf)
{
  __shared__ bf16 P [64*SP];
  __shared__ bf16 Sm[64*SP];
  __shared__ float ksum_lds[64];
  const int bx = blockIdx.x;
  const int bh = bx >> 4, seg = bx & (NSEG-1);
  const int b = bh>>4, h = bh&15;
  const int tid = threadIdx.x;
  const int w = tid >> 6, lane = tid & 63;
  const int lrow = lane&15, g4 = lane>>4, lk8 = g4*8;
  const bf16* ktb = Kt + (size_t)bh*HD*LL + seg*128;
  const bf16* vtb = Vt + (size_t)bh*HD*LL + seg*128;

  // init: segment-prefix state -> Sm (bf16), ksum_lds (fp32)
  if (tid < 64) ksum_lds[tid] = ksxb[(size_t)bx*64 + tid];
  {
    const bf16* sp = Sexb + (size_t)bx*4096 + tid*16;
    bf16x8 s0 = *(const bf16x8*)&sp[0], s1 = *(const bf16x8*)&sp[8];
    const int e = tid>>2, d0 = (tid&3)*16;
    *(bf16x8*)&Sm[e*SP + d0]     = s0;
    *(bf16x8*)&Sm[e*SP + d0 + 8] = s1;
  }
  __syncthreads();
  // running state fp32 (e-strip of wave w)
  f32x4 Srun[4];
  #pragma unroll
  for (int j=0;j<4;j++)
    #pragma unroll
    for (int r=0;r<4;r++)
      Srun[j][r] = (float)Sm[(w*16+g4*4+r)*SP + j*16+lrow];

  #pragma unroll
  for (int c=0;c<2;c++){
    const int cg = seg*2 + c;
    const bf16* kb = Kn + ((size_t)(b*LL + cg*CHUNK))*HID + h*HD;
    const bf16* qb = Q  + ((size_t)(b*LL + cg*CHUNK))*HID + h*HD;
    // Q strip (own rows) + K row-major frags
    bf16x8 aq[2], bk[4][2];
    #pragma unroll
    for (int kk=0;kk<2;kk++){
      aq[kk] = *(const bf16x8*)&qb[(size_t)(w*16+lrow)*HID + kk*32 + lk8];
      #pragma unroll
      for (int j=0;j<4;j++)
        bk[j][kk] = *(const bf16x8*)&kb[(size_t)(j*16+lrow)*HID + kk*32 + lk8];
    }
    // QK^T strip
    f32x4 sacc[4] = {};
    #pragma unroll
    for (int kk=0;kk<2;kk++)
      #pragma unroll
      for (int j=0;j<4;j++)
        sacc[j] = mfma16(aq[kk], bk[j][kk], sacc[j]);
    // causal mask + row sums
    float rs[4];
    #pragma unroll
    for (int r=0;r<4;r++){
      int irow = w*16 + g4*4 + r;
      float p = 0.f;
      #pragma unroll
      for (int j=0;j<4;j++){
        int jcol = j*16 + lrow;
        float v = (jcol <= irow) ? sacc[j][r] : 0.f;
        sacc[j][r] = v;
        p += v;
      }
      p += __shfl_xor(p,1); p += __shfl_xor(p,2);
      p += __shfl_xor(p,4); p += __shfl_xor(p,8);
      rs[r] = p;
    }
    // zA = q_row . ksum_state
    float zA;
    {
      float s = 0.f;
      #pragma unroll
      for (int kk=0;kk<2;kk++){
        const float* k8 = ksum_lds + kk*32 + lk8;
        bf16x8 q = aq[kk];
        #pragma unroll
        for (int j=0;j<8;j++) s += (float)q[j] * k8[j];
      }
      s += __shfl_xor(s,16); s += __shfl_xor(s,32);
      zA = s;
    }
    // inter: oacc = Q @ S_state^T (B-frags from Sm)
    f32x4 oacc[4] = {};
    #pragma unroll
    for (int kk=0;kk<2;kk++)
      #pragma unroll
      for (int j=0;j<4;j++){
        bf16x8 bs = *(const bf16x8*)&Sm[(j*16+lrow)*SP + kk*32 + lk8];
        oacc[j] = mfma16(aq[kk], bs, oacc[j]);
      }
    // P strip -> LDS
    #pragma unroll
    for (int j=0;j<4;j++)
      #pragma unroll
      for (int r=0;r<4;r++)
        P[(w*16+g4*4+r)*SP + j*16+lrow] = (bf16)sacc[j][r];
    __syncthreads();                     // P ready; Sm inter-reads done
    // intra: oacc += P @ V  (V^T frags from global Vt)
    #pragma unroll
    for (int kk=0;kk<2;kk++){
      bf16x8 ap = *(const bf16x8*)&P[(w*16+lrow)*SP + kk*32 + lk8];
      #pragma unroll
      for (int j=0;j<4;j++){
        bf16x8 bv = *(const bf16x8*)&vtb[(size_t)(j*16+lrow)*LL + c*64 + kk*32 + lk8];
        oacc[j] = mfma16(ap, bv, oacc[j]);
      }
    }
    // normalize + store
    bf16* ob = Obuf + ((size_t)(b*LL + cg*CHUNK))*HID + h*HD;
    #pragma unroll
    for (int r=0;r<4;r++){
      float z = __shfl(zA, g4*4 + r) + rs[r];
      z = fmaxf(z, 1e-6f);
      float inv = 1.0f/z;
      int irow = w*16 + g4*4 + r;
      #pragma unroll
      for (int j=0;j<4;j++)
        ob[(size_t)irow*HID + j*16+lrow] = (bf16)(oacc[j][r]*inv);
    }
    if (c==0){
      // S_run += V^T K (e-strip of wave w), frags from global Kt/Vt
      #pragma unroll
      for (int kk=0;kk<2;kk++){
        bf16x8 fa = *(const bf16x8*)&vtb[(size_t)(w*16+lrow)*LL + kk*32 + lk8];
        #pragma unroll
        for (int j=0;j<4;j++){
          bf16x8 fb = *(const bf16x8*)&ktb[(size_t)(j*16+lrow)*LL + kk*32 + lk8];
          Srun[j] = mfma16(fa, fb, Srun[j]);
        }
      }
      // ksum update: rows d = w*16+lrow, l-segment g4*16 of chunk 0
      {
        float s = 0.f;
        const bf16* kr = ktb + (size_t)(w*16+lrow)*LL + g4*16;
        #pragma unroll
        for (int u=0;u<2;u++){
          bf16x8 k8 = *(const bf16x8*)&kr[u*8];
          #pragma unroll
          for (int e=0;e<8;e++) s += (float)k8[e];
        }
        s += __shfl_xor(s,16); s += __shfl_xor(s,32);
        if (g4==0) ksum_lds[w*16+lrow] += s;
      }
      // mirror updated state to Sm (own e-strip)
      #pragma unroll
      for (int j=0;j<4;j++)
        #pragma unroll
        for (int r=0;r<4;r++)
          Sm[(w*16+g4*4+r)*SP + j*16+lrow] = (bf16)Srun[j][r];
      __syncthreads();                   // Sm/ksum updates visible before chunk 1
    }
  }
}

// ---------------- launch ----------------
extern "C" void kernel_launch(void* const* d_in, const int* in_sizes, int n_in,
                              void* d_out, int out_size, void* d_ws, size_t ws_size,
                              hipStream_t stream)
{
  const float* x  = (const float*)d_in[0];
  const float* Wq = (const float*)d_in[1];
  const float* Wk = (const float*)d_in[2];
  const float* Wv = (const float*)d_in[3];
  const float* Wo = (const float*)d_in[4];
  float* out = (float*)d_out;

  char* p = (char*)d_ws;
  auto alloc = [&](size_t bytes){ void* r = (void*)p; p += (bytes + 255) & ~(size_t)255; return r; };
  bf16* xb   = (bf16*)alloc((size_t)MM*HID*2);
  bf16* Wqb  = (bf16*)alloc((size_t)HID*HID*2);
  bf16* Wkb  = (bf16*)alloc((size_t)HID*HID*2);
  bf16* Wvb  = (bf16*)alloc((size_t)HID*HID*2);
  bf16* Wob  = (bf16*)alloc((size_t)HID*HID*2);
  bf16* Qb   = (bf16*)alloc((size_t)MM*HID*2);
  bf16* Knb  = (bf16*)alloc((size_t)MM*HID*2);
  bf16* Ktb  = (bf16*)alloc((size_t)MM*HID*2);        // (BH, D, L)
  bf16* Vtb  = (bf16*)alloc((size_t)MM*HID*2);        // (BH, D, L)
  bf16* Ob   = (bf16*)alloc((size_t)MM*HID*2);
  float* Sseg = (float*)alloc((size_t)BHn*NSEG*4096*4);  // 8 MB
  bf16*  Sexb = (bf16*) alloc((size_t)BHn*NSEG*4096*2);  // 4 MB
  float* kseg = (float*)alloc((size_t)BHn*NSEG*64*4);
  float* ksxb = (float*)alloc((size_t)BHn*NSEG*64*4);

  cast_all_k<<<dim3(4096), 256, 0, stream>>>(x, Wq,Wk,Wv,Wo, xb, Wqb,Wkb,Wvb,Wob);
  gemm8_k<0><<<dim3(24,32), 512, 0, stream>>>(xb, Wqb,Wkb,Wvb, Qb,Knb,Ktb,Vtb, nullptr);
  segsum_k<<<dim3(BHn*NSEG), 256, 0, stream>>>(Ktb, Vtb, Sseg, kseg);
  segscan_k<<<dim3((BHn*4096 + BHn*64 + 255)/256), 256, 0, stream>>>(Sseg, kseg, Sexb, ksxb);
  attn_k<<<dim3(BHn*NSEG), 256, 0, stream>>>(Qb, Knb, Ktb, Vtb, Sexb, ksxb, Ob);
  gemm8_k<1><<<dim3(8,32), 512, 0, stream>>>(Ob, Wob,nullptr,nullptr, nullptr,nullptr,nullptr,nullptr, out);
}

// Round 10
// 155.756 us; speedup vs baseline: 1.0374x; 1.0374x over previous
//
#include <hip/hip_runtime.h>
#include <cstdint>
#include <cstddef>

#define HID 1024
#define NH 16
#define HD 64
#define BB 2
#define LL 2048
#define MM (BB*LL)       // 4096 rows
#define CHUNK 64
#define NSEG 16          // segments per (b,h): 128 rows each (2 chunks)
#define BHn (BB*NH)      // 32 (b,h) chains
#define SP 72            // LDS pad stride (multiple of 8 for b128 reads)

typedef __bf16 bf16;
typedef __attribute__((ext_vector_type(8))) __bf16 bf16x8;
typedef __attribute__((ext_vector_type(4))) float f32x4;

__device__ __forceinline__ f32x4 mfma16(bf16x8 a, bf16x8 b, f32x4 c){
  return __builtin_amdgcn_mfma_f32_16x16x32_bf16(a, b, c, 0, 0, 0);
}

__device__ __forceinline__ void gload16(const void* g, void* l){
  __builtin_amdgcn_global_load_lds(
      (const __attribute__((address_space(1))) unsigned int*)g,
      (__attribute__((address_space(3))) unsigned int*)l, 16, 0, 0);
}

__device__ __forceinline__ void barx(){
  asm volatile("" ::: "memory");
  __builtin_amdgcn_s_barrier();
  asm volatile("" ::: "memory");
}

#define WAITVM(N) asm volatile("s_waitcnt vmcnt(" #N ")" ::: "memory")

// ---------------- fused cast fp32 -> bf16, 8 elems/thread ----------------
__global__ __launch_bounds__(256) void cast_all_k(
    const float* __restrict__ x,  const float* __restrict__ w0,
    const float* __restrict__ w1, const float* __restrict__ w2, const float* __restrict__ w3,
    bf16* __restrict__ xb, bf16* __restrict__ d0, bf16* __restrict__ d1,
    bf16* __restrict__ d2, bf16* __restrict__ d3)
{
  int bid = blockIdx.x;                   // 0..4095
  const float* s; bf16* d; int base;
  if (bid < 2048){ s = x; d = xb; base = bid; }           // 4M elems
  else {
    int w = (bid - 2048) >> 9, r = (bid - 2048) & 511;    // 1M elems each
    s = (w==0)?w0:(w==1)?w1:(w==2)?w2:w3;
    d = (w==0)?d0:(w==1)?d1:(w==2)?d2:d3;
    base = r;
  }
  size_t i = (size_t)(base*256 + threadIdx.x) * 8;
  float4 v0 = *(const float4*)(s + i);
  float4 v1 = *(const float4*)(s + i + 4);
  union { bf16 h[8]; uint4 u; } pk;
  pk.h[0]=(bf16)v0.x; pk.h[1]=(bf16)v0.y; pk.h[2]=(bf16)v0.z; pk.h[3]=(bf16)v0.w;
  pk.h[4]=(bf16)v1.x; pk.h[5]=(bf16)v1.y; pk.h[6]=(bf16)v1.z; pk.h[7]=(bf16)v1.w;
  *(uint4*)(d + i) = pk.u;
}

// ---------------- software-pipelined 8-wave 128x128 GEMM, 3 LDS buffers ----------------
// C[m,n] = sum_k A[m,k]*W[n,k].  BK=32, NKT=32 K-tiles.
// LDS = 3 bufs x {A,B} x 128x32 bf16 = 48 KiB -> 3 blocks/CU (24 waves/CU).
// Pipeline: stage tile t+2 at iter t; steady-state vmcnt(2) (tile t+1 landed,
// tile t+2 in flight); barrier; ds_read frags(t+1) into spare reg set; MFMA(t).
// Buffer lifetime: stage(t+2) targets buf (t+2)%3 == (t-1)%3, whose reads
// finished at the barrier closing iter t-2 -> safe.
// MODE 0: QKV fused, grid (24,32): wsel=bn>>3, bn&=7; elu+1 on Q,K.
// MODE 1: out-proj, grid (8,32), fp32 store.
template<int MODE>
__global__ __launch_bounds__(512, 2) void gemm8_k(
    const bf16* __restrict__ A,
    const bf16* __restrict__ W0, const bf16* __restrict__ W1, const bf16* __restrict__ W2,
    bf16* __restrict__ Qo, bf16* __restrict__ Kn, bf16* __restrict__ Vn,
    float* __restrict__ Outf)
{
  constexpr int NKT = HID/32;
  __shared__ bf16 lds[3][2][128*32];             // 48 KiB

  const int tid = threadIdx.x;
  const int wv = tid >> 6, lane = tid & 63;
  const int lrow = lane & 15, g4 = lane >> 4;
  const int wr = wv >> 2, wc = wv & 3;
  int bn = blockIdx.x, wsel = 0;
  const bf16* W = W0;
  if (MODE==0){ wsel = bn >> 3; bn &= 7; W = (wsel==0)?W0:((wsel==1)?W1:W2); }
  const int row0 = blockIdx.y*128, col0 = bn*128;

  const int sr = tid >> 2, sc = tid & 3;
  const int scs = sc ^ ((sr>>1)&3);              // pre-swizzled source chunk
  const bf16* gA = A + (size_t)(row0 + sr)*HID + scs*8;
  const bf16* gB = W + (size_t)(col0 + sr)*HID + scs*8;
  const int ldst = tid*8;

  auto stage_tile = [&](int u){
    const int buf = u % 3;
    gload16(gA + u*32, (void*)&lds[buf][0][ldst]);
    gload16(gB + u*32, (void*)&lds[buf][1][ldst]);
  };

  const int koff = (g4 ^ ((lrow>>1)&3)) << 3;    // swizzled chunk on read

  auto read_frags = [&](int u, bf16x8 (&fa)[4], bf16x8 (&fb)[2]){
    const int buf = u % 3;
    #pragma unroll
    for (int i=0;i<4;i++)
      fa[i] = *(const bf16x8*)&lds[buf][0][((wr*64 + i*16+lrow)<<5) + koff];
    #pragma unroll
    for (int j=0;j<2;j++)
      fb[j] = *(const bf16x8*)&lds[buf][1][((wc*32 + j*16+lrow)<<5) + koff];
  };

  f32x4 acc[4][2] = {};
  auto do_mfma = [&](bf16x8 (&fa)[4], bf16x8 (&fb)[2]){
    __builtin_amdgcn_s_setprio(1);
    #pragma unroll
    for (int i=0;i<4;i++)
      #pragma unroll
      for (int j=0;j<2;j++)
        acc[i][j] = mfma16(fa[i], fb[j], acc[i][j]);
    __builtin_amdgcn_s_setprio(0);
  };

  stage_tile(0); stage_tile(1);
  WAITVM(2);                                     // tile 0 landed
  barx();
  bf16x8 fEa[4], fEb[2], fOa[4], fOb[2];
  read_frags(0, fEa, fEb);

  for (int t=0; t<NKT; t+=2){
    // ---- even iter: cur=E, next->O ----
    if (t+2 < NKT){ stage_tile(t+2); WAITVM(2); }
    else          { WAITVM(0); }
    barx();
    read_frags(t+1, fOa, fOb);
    do_mfma(fEa, fEb);
    // ---- odd iter: cur=O, next->E ----
    const int t2 = t+1;
    if (t2 < NKT-1){
      if (t2+2 < NKT){ stage_tile(t2+2); WAITVM(2); }
      else           { WAITVM(0); }
      barx();
      read_frags(t2+1, fEa, fEb);
    }
    do_mfma(fOa, fOb);
  }

  #pragma unroll
  for (int i=0;i<4;i++){
    const int m0 = row0 + wr*64 + i*16 + g4*4;
    #pragma unroll
    for (int j=0;j<2;j++){
      const int c = col0 + wc*32 + j*16 + lrow;
      #pragma unroll
      for (int r=0;r<4;r++){
        float v = acc[i][j][r];
        if (MODE==1){
          Outf[(size_t)(m0+r)*HID + c] = v;
        } else {
          if (wsel<2) v = v>0.f ? v+1.f : __expf(v);   // elu(v)+1
          bf16 bv = (bf16)v;
          if      (wsel==0) Qo[(size_t)(m0+r)*HID + c] = bv;
          else if (wsel==1) Kn[(size_t)(m0+r)*HID + c] = bv;
          else              Vn[(size_t)(m0+r)*HID + c] = bv;
        }
      }
    }
  }
}

// ---------------- segsum: per-(b,h,seg) sum of k (x) v over 128 rows + ksum ----------------
// grid = BHn*NSEG = 512 blocks x 256 thr. Wave we owns e-strip [we*16, we*16+16).
__global__ __launch_bounds__(256, 2) void segsum_k(const bf16* __restrict__ Kn, const bf16* __restrict__ Vn,
                                                   float* __restrict__ Sseg, float* __restrict__ kseg)
{
  __shared__ bf16 KT[64*SP];
  __shared__ bf16 VT[64*SP];
  const int bx = blockIdx.x;
  const int bh = bx >> 4, seg = bx & (NSEG-1);
  const int b = bh>>4, h = bh&15;
  const int tid = threadIdx.x;
  const int we = tid >> 6, lane = tid & 63;
  const int lrow = lane&15, g4 = lane>>4, lk8 = g4*8;
  const int sj = tid >> 2, c4 = tid & 3;

  f32x4 acc[4] = {};
  float krow = 0.f;

  #pragma unroll
  for (int c=0;c<2;c++){
    const int cg = seg*2 + c;
    const bf16* kb = Kn + ((size_t)(b*LL + cg*CHUNK))*HID + h*HD;
    const bf16* vb = Vn + ((size_t)(b*LL + cg*CHUNK))*HID + h*HD;
    {
      const bf16* ks = kb + (size_t)sj*HID + c4*16;
      const bf16* vs = vb + (size_t)sj*HID + c4*16;
      bf16x8 kr0 = *(const bf16x8*)&ks[0], kr1 = *(const bf16x8*)&ks[8];
      bf16x8 vr0 = *(const bf16x8*)&vs[0], vr1 = *(const bf16x8*)&vs[8];
      #pragma unroll
      for (int e=0;e<8;e++){
        KT[(c4*16+e)*SP + sj]   = kr0[e];
        KT[(c4*16+8+e)*SP + sj] = kr1[e];
        VT[(c4*16+e)*SP + sj]   = vr0[e];
        VT[(c4*16+8+e)*SP + sj] = vr1[e];
      }
    }
    __syncthreads();
    #pragma unroll
    for (int kk=0;kk<2;kk++){
      bf16x8 fa = *(const bf16x8*)&VT[(we*16 + lrow)*SP + kk*32 + lk8];
      #pragma unroll
      for (int j=0;j<4;j++){
        bf16x8 fb = *(const bf16x8*)&KT[(j*16 + lrow)*SP + kk*32 + lk8];
        acc[j] = mfma16(fa, fb, acc[j]);
      }
    }
    {
      const int row = we*16 + lrow;
      float s = 0.f;
      #pragma unroll
      for (int u=0;u<2;u++){
        bf16x8 k8 = *(const bf16x8*)&KT[row*SP + g4*16 + u*8];
        #pragma unroll
        for (int e=0;e<8;e++) s += (float)k8[e];
      }
      s += __shfl_xor(s,16); s += __shfl_xor(s,32);
      krow += s;                                 // only meaningful on g4==0 lanes
    }
    __syncthreads();                             // protect KT/VT overwrite
  }

  float* so = Sseg + (size_t)bx*4096;
  #pragma unroll
  for (int j=0;j<4;j++)
    #pragma unroll
    for (int r=0;r<4;r++)
      so[(we*16 + g4*4 + r)*64 + j*16 + lrow] = acc[j][r];
  if (g4==0) kseg[(size_t)bx*64 + we*16 + lrow] = krow;
}

// ---------------- segscan: exclusive prefix over NSEG segments ----------------
__global__ __launch_bounds__(256) void segscan_k(const float* __restrict__ Sseg, const float* __restrict__ kseg,
                                                 bf16* __restrict__ Sexb, float* __restrict__ ksxb)
{
  int gid = blockIdx.x*256 + threadIdx.x;
  if (gid < BHn*4096){
    int bh = gid >> 12, e = gid & 4095;
    float run = 0.f;
    size_t base = (size_t)bh*NSEG*4096 + e;
    #pragma unroll 4
    for (int s=0;s<NSEG;s++){
      Sexb[base + (size_t)s*4096] = (bf16)run;
      run += Sseg[base + (size_t)s*4096];
    }
  } else if (gid < BHn*4096 + BHn*64){
    int g2 = gid - BHn*4096;
    int bh = g2 >> 6, d = g2 & 63;
    float run = 0.f;
    size_t base = (size_t)bh*NSEG*64 + d;
    #pragma unroll 4
    for (int s=0;s<NSEG;s++){
      ksxb[base + (size_t)s*64] = run;
      run += kseg[base + (size_t)s*64];
    }
  }
}

// ---------------- attn: per-(b,h,seg) output for 2 chunks, state kept on-chip ----------
__global__ __launch_bounds__(256, 2) void attn_k(const bf16* __restrict__ Q, const bf16* __restrict__ Kn,
                                                 const bf16* __restrict__ Vn, const bf16* __restrict__ Sexb,
                                                 const float* __restrict__ ksxb, bf16* __restrict__ Obuf)
{
  __shared__ bf16 KT[64*SP];
  __shared__ bf16 VT[64*SP];
  __shared__ bf16 P [64*SP];
  __shared__ bf16 Sm[64*SP];
  __shared__ float ksum_lds[64];
  const int bx = blockIdx.x;
  const int bh = bx >> 4, seg = bx & (NSEG-1);
  const int b = bh>>4, h = bh&15;
  const int tid = threadIdx.x;
  const int w = tid >> 6, lane = tid & 63;
  const int lrow = lane&15, g4 = lane>>4, lk8 = g4*8;
  const int sj = tid >> 2, c4 = tid & 3;

  // init: segment-prefix state -> Sm (bf16) and ksum_lds (fp32)
  if (tid < 64) ksum_lds[tid] = ksxb[(size_t)bx*64 + tid];
  {
    const bf16* sp = Sexb + (size_t)bx*4096 + tid*16;
    bf16x8 s0 = *(const bf16x8*)&sp[0], s1 = *(const bf16x8*)&sp[8];
    const int e = tid>>2, d0 = (tid&3)*16;
    *(bf16x8*)&Sm[e*SP + d0]     = s0;
    *(bf16x8*)&Sm[e*SP + d0 + 8] = s1;
  }
  __syncthreads();
  // running state fp32, e-strip C-layout: rows w*16+g4*4+r, cols j*16+lrow
  f32x4 Srun[4];
  #pragma unroll
  for (int j=0;j<4;j++)
    #pragma unroll
    for (int r=0;r<4;r++)
      Srun[j][r] = (float)Sm[(w*16+g4*4+r)*SP + j*16+lrow];

  #pragma unroll
  for (int c=0;c<2;c++){
    const int cg = seg*2 + c;
    const bf16* kb = Kn + ((size_t)(b*LL + cg*CHUNK))*HID + h*HD;
    const bf16* vb = Vn + ((size_t)(b*LL + cg*CHUNK))*HID + h*HD;
    const bf16* qb = Q  + ((size_t)(b*LL + cg*CHUNK))*HID + h*HD;
    // stage K,V transposed into KT,VT
    {
      const bf16* ks = kb + (size_t)sj*HID + c4*16;
      const bf16* vs = vb + (size_t)sj*HID + c4*16;
      bf16x8 kr0 = *(const bf16x8*)&ks[0], kr1 = *(const bf16x8*)&ks[8];
      bf16x8 vr0 = *(const bf16x8*)&vs[0], vr1 = *(const bf16x8*)&vs[8];
      #pragma unroll
      for (int e=0;e<8;e++){
        KT[(c4*16+e)*SP + sj]   = kr0[e];
        KT[(c4*16+8+e)*SP + sj] = kr1[e];
        VT[(c4*16+e)*SP + sj]   = vr0[e];
        VT[(c4*16+8+e)*SP + sj] = vr1[e];
      }
    }
    // Q strip (own rows) + K direct frags (row-major)
    bf16x8 aq[2], bk[4][2];
    #pragma unroll
    for (int kk=0;kk<2;kk++){
      aq[kk] = *(const bf16x8*)&qb[(size_t)(w*16+lrow)*HID + kk*32 + lk8];
      #pragma unroll
      for (int j=0;j<4;j++)
        bk[j][kk] = *(const bf16x8*)&kb[(size_t)(j*16+lrow)*HID + kk*32 + lk8];
    }
    __syncthreads();                     // KT/VT ready; Sm/ksum from prev iter ready
    // QK^T strip
    f32x4 sacc[4] = {};
    #pragma unroll
    for (int kk=0;kk<2;kk++)
      #pragma unroll
      for (int j=0;j<4;j++)
        sacc[j] = mfma16(aq[kk], bk[j][kk], sacc[j]);
    // causal mask + row sums
    float rs[4];
    #pragma unroll
    for (int r=0;r<4;r++){
      int irow = w*16 + g4*4 + r;
      float p = 0.f;
      #pragma unroll
      for (int j=0;j<4;j++){
        int jcol = j*16 + lrow;
        float v = (jcol <= irow) ? sacc[j][r] : 0.f;
        sacc[j][r] = v;
        p += v;
      }
      p += __shfl_xor(p,1); p += __shfl_xor(p,2);
      p += __shfl_xor(p,4); p += __shfl_xor(p,8);
      rs[r] = p;
    }
    // zA = q_row . ksum_state
    float zA;
    {
      float s = 0.f;
      #pragma unroll
      for (int kk=0;kk<2;kk++){
        const float* k8 = ksum_lds + kk*32 + lk8;
        bf16x8 q = aq[kk];
        #pragma unroll
        for (int j=0;j<8;j++) s += (float)q[j] * k8[j];
      }
      s += __shfl_xor(s,16); s += __shfl_xor(s,32);
      zA = s;
    }
    // inter: oacc = Q @ S_state^T (B-frags from Sm)
    f32x4 oacc[4] = {};
    #pragma unroll
    for (int kk=0;kk<2;kk++)
      #pragma unroll
      for (int j=0;j<4;j++){
        bf16x8 bs = *(const bf16x8*)&Sm[(j*16+lrow)*SP + kk*32 + lk8];
        oacc[j] = mfma16(aq[kk], bs, oacc[j]);
      }
    // P strip -> LDS
    #pragma unroll
    for (int j=0;j<4;j++)
      #pragma unroll
      for (int r=0;r<4;r++)
        P[(w*16+g4*4+r)*SP + j*16+lrow] = (bf16)sacc[j][r];
    __syncthreads();                     // P ready; all Sm/KT-for-QK reads done
    // intra: oacc += P @ V
    #pragma unroll
    for (int kk=0;kk<2;kk++){
      bf16x8 ap = *(const bf16x8*)&P[(w*16+lrow)*SP + kk*32 + lk8];
      #pragma unroll
      for (int j=0;j<4;j++){
        bf16x8 bv = *(const bf16x8*)&VT[(j*16+lrow)*SP + kk*32 + lk8];
        oacc[j] = mfma16(ap, bv, oacc[j]);
      }
    }
    // normalize + store
    bf16* ob = Obuf + ((size_t)(b*LL + cg*CHUNK))*HID + h*HD;
    #pragma unroll
    for (int r=0;r<4;r++){
      float z = __shfl(zA, g4*4 + r) + rs[r];
      z = fmaxf(z, 1e-6f);
      float inv = 1.0f/z;
      int irow = w*16 + g4*4 + r;
      #pragma unroll
      for (int j=0;j<4;j++)
        ob[(size_t)irow*HID + j*16+lrow] = (bf16)(oacc[j][r]*inv);
    }
    if (c==0){
      // S_run += V^T K (e-strip), then mirror to Sm
      #pragma unroll
      for (int kk=0;kk<2;kk++){
        bf16x8 fa = *(const bf16x8*)&VT[(w*16+lrow)*SP + kk*32 + lk8];
        #pragma unroll
        for (int j=0;j<4;j++){
          bf16x8 fb = *(const bf16x8*)&KT[(j*16+lrow)*SP + kk*32 + lk8];
          Srun[j] = mfma16(fa, fb, Srun[j]);
        }
      }
      // ksum update (rows of KT)
      {
        const int row = w*16 + lrow;
        float s = 0.f;
        #pragma unroll
        for (int u=0;u<2;u++){
          bf16x8 k8 = *(const bf16x8*)&KT[row*SP + g4*16 + u*8];
          #pragma unroll
          for (int e=0;e<8;e++) s += (float)k8[e];
        }
        s += __shfl_xor(s,16); s += __shfl_xor(s,32);
        if (g4==0) ksum_lds[row] += s;
      }
      #pragma unroll
      for (int j=0;j<4;j++)
        #pragma unroll
        for (int r=0;r<4;r++)
          Sm[(w*16+g4*4+r)*SP + j*16+lrow] = (bf16)Srun[j][r];
    }
    __syncthreads();                     // Sm/ksum updates + VT reads done before next stage
  }
}

// ---------------- launch ----------------
extern "C" void kernel_launch(void* const* d_in, const int* in_sizes, int n_in,
                              void* d_out, int out_size, void* d_ws, size_t ws_size,
                              hipStream_t stream)
{
  const float* x  = (const float*)d_in[0];
  const float* Wq = (const float*)d_in[1];
  const float* Wk = (const float*)d_in[2];
  const float* Wv = (const float*)d_in[3];
  const float* Wo = (const float*)d_in[4];
  float* out = (float*)d_out;

  char* p = (char*)d_ws;
  auto alloc = [&](size_t bytes){ void* r = (void*)p; p += (bytes + 255) & ~(size_t)255; return r; };
  bf16* xb   = (bf16*)alloc((size_t)MM*HID*2);
  bf16* Wqb  = (bf16*)alloc((size_t)HID*HID*2);
  bf16* Wkb  = (bf16*)alloc((size_t)HID*HID*2);
  bf16* Wvb  = (bf16*)alloc((size_t)HID*HID*2);
  bf16* Wob  = (bf16*)alloc((size_t)HID*HID*2);
  bf16* Qb   = (bf16*)alloc((size_t)MM*HID*2);
  bf16* Knb  = (bf16*)alloc((size_t)MM*HID*2);
  bf16* Vnb  = (bf16*)alloc((size_t)MM*HID*2);
  bf16* Ob   = (bf16*)alloc((size_t)MM*HID*2);
  float* Sseg = (float*)alloc((size_t)BHn*NSEG*4096*4);  // 8 MB
  bf16*  Sexb = (bf16*) alloc((size_t)BHn*NSEG*4096*2);  // 4 MB
  float* kseg = (float*)alloc((size_t)BHn*NSEG*64*4);
  float* ksxb = (float*)alloc((size_t)BHn*NSEG*64*4);

  cast_all_k<<<dim3(4096), 256, 0, stream>>>(x, Wq,Wk,Wv,Wo, xb, Wqb,Wkb,Wvb,Wob);
  gemm8_k<0><<<dim3(24,32), 512, 0, stream>>>(xb, Wqb,Wkb,Wvb, Qb,Knb,Vnb, nullptr);
  segsum_k<<<dim3(BHn*NSEG), 256, 0, stream>>>(Knb, Vnb, Sseg, kseg);
  segscan_k<<<dim3((BHn*4096 + BHn*64 + 255)/256), 256, 0, stream>>>(Sseg, kseg, Sexb, ksxb);
  attn_k<<<dim3(BHn*NSEG), 256, 0, stream>>>(Qb, Knb, Vnb, Sexb, ksxb, Ob);
  gemm8_k<1><<<dim3(8,32), 512, 0, stream>>>(Ob, Wob,nullptr,nullptr, nullptr,nullptr,nullptr, out);
}